// Round 19
// baseline (613.082 us; speedup 1.0000x reference)
//
#include <hip/hip_runtime.h>
#include <math.h>

typedef __attribute__((ext_vector_type(8))) short bf16x8;
typedef __attribute__((ext_vector_type(4))) float f32x4;

__device__ __forceinline__ ushort f2b(float f) {
    union { float f; unsigned u; } v; v.f = f;
    unsigned r = (v.u + 0x7FFFu + ((v.u >> 16) & 1u)) >> 16;
    return (ushort)r;
}
__device__ __forceinline__ float b2f(ushort h) {
    union { unsigned u; float f; } v; v.u = ((unsigned)h) << 16;
    return v.f;
}

// ---------- Laplacian pipeline ----------

// single block: row stats (ddof=1) for 3 rows kept in LDS, then Xn/sq write
__global__ __launch_bounds__(256) void k_prep(const float* __restrict__ X,
                                              float* __restrict__ Xn,
                                              float* __restrict__ sq, int N) {
    __shared__ double sh_s[256], sh_ss[256];
    __shared__ float sst[3];
    int t = threadIdx.x;
    for (int r = 0; r < 3; r++) {
        const float* row = X + (size_t)r * N;
        double s = 0.0, ss = 0.0;
        for (int i = t * 4; i < N; i += 1024) {
            float4 v = *(const float4*)(row + i);
            s += (double)v.x + (double)v.y + (double)v.z + (double)v.w;
            ss += (double)v.x * v.x + (double)v.y * v.y + (double)v.z * v.z + (double)v.w * v.w;
        }
        sh_s[t] = s; sh_ss[t] = ss; __syncthreads();
        for (int off = 128; off > 0; off >>= 1) {
            if (t < off) { sh_s[t] += sh_s[t + off]; sh_ss[t] += sh_ss[t + off]; }
            __syncthreads();
        }
        if (t == 0) {
            double mean = sh_s[0] / N;
            double var = (sh_ss[0] - mean * sh_s[0]) / (N - 1);
            if (var < 0.0) var = 0.0;
            sst[r] = 1.0f / ((float)sqrt(var) + 0.01f);
        }
        __syncthreads();
    }
    float s0 = sst[0], s1 = sst[1], s2 = sst[2];
    for (int i = t * 4; i < N; i += 1024) {
        float4 v0 = *(const float4*)(X + i);
        float4 v1 = *(const float4*)(X + N + i);
        float4 v2 = *(const float4*)(X + 2 * N + i);
        v0.x *= s0; v0.y *= s0; v0.z *= s0; v0.w *= s0;
        v1.x *= s1; v1.y *= s1; v1.z *= s1; v1.w *= s1;
        v2.x *= s2; v2.y *= s2; v2.z *= s2; v2.w *= s2;
        *(float4*)(Xn + i) = v0;
        *(float4*)(Xn + N + i) = v1;
        *(float4*)(Xn + 2 * N + i) = v2;
        float4 sv;
        sv.x = v0.x * v0.x + v1.x * v1.x + v2.x * v2.x;
        sv.y = v0.y * v0.y + v1.y * v1.y + v2.y * v2.y;
        sv.z = v0.z * v0.z + v1.z * v1.z + v2.z * v2.z;
        sv.w = v0.w * v0.w + v1.w * v1.w + v2.w * v2.w;
        *(float4*)(sq + i) = sv;
    }
}

// one block per row i: W row from vectorized Xn/sq, row-sum in-block, finalize, write bf16 L
template<int CPT>
__global__ __launch_bounds__(256) void k_lap(const float* __restrict__ Xn,
                                             const float* __restrict__ sq,
                                             const float* __restrict__ m,
                                             ushort* __restrict__ L, int N) {
    int i = blockIdx.x;
    int t = threadIdx.x;
    int T = blockDim.x;
    float a0 = Xn[i], a1 = Xn[N + i], a2 = Xn[2 * N + i];
    float si = sq[i];
    int j0 = t * CPT;
    float w[CPT];
    float psum = 0.f;
    #pragma unroll
    for (int q4 = 0; q4 < CPT / 4; q4++) {
        int j = j0 + q4 * 4;
        float4 x0 = *(const float4*)(Xn + j);
        float4 x1 = *(const float4*)(Xn + N + j);
        float4 x2 = *(const float4*)(Xn + 2 * N + j);
        float4 sv = *(const float4*)(sq + j);
        float D;
        D = fmaxf(si + sv.x - 2.f * (a0 * x0.x + a1 * x1.x + a2 * x2.x), 0.f);
        w[q4 * 4 + 0] = exp2f(-D * 0.14426950408889634f);
        D = fmaxf(si + sv.y - 2.f * (a0 * x0.y + a1 * x1.y + a2 * x2.y), 0.f);
        w[q4 * 4 + 1] = exp2f(-D * 0.14426950408889634f);
        D = fmaxf(si + sv.z - 2.f * (a0 * x0.z + a1 * x1.z + a2 * x2.z), 0.f);
        w[q4 * 4 + 2] = exp2f(-D * 0.14426950408889634f);
        D = fmaxf(si + sv.w - 2.f * (a0 * x0.w + a1 * x1.w + a2 * x2.w), 0.f);
        w[q4 * 4 + 3] = exp2f(-D * 0.14426950408889634f);
        psum += w[q4 * 4] + w[q4 * 4 + 1] + w[q4 * 4 + 2] + w[q4 * 4 + 3];
    }
    __shared__ float red[256];
    red[t] = psum; __syncthreads();
    for (int off = T >> 1; off > 0; off >>= 1) {
        if (t < off) red[t] += red[t + off];
        __syncthreads();
    }
    float d = red[0];
    float mi = m[i];
    ushort* Lo = L + (size_t)i * N + j0;
    #pragma unroll
    for (int q4 = 0; q4 < CPT / 4; q4++) {
        int j = j0 + q4 * 4;
        float4 mj = *(const float4*)(m + j);
        ushort o[4];
        float lv;
        lv = ((j + 0 == i) ? d : 0.f) - w[q4 * 4 + 0]; lv = mi * mj.x * lv; if (j + 0 == i) lv += 1.f - mj.x; o[0] = f2b(lv);
        lv = ((j + 1 == i) ? d : 0.f) - w[q4 * 4 + 1]; lv = mi * mj.y * lv; if (j + 1 == i) lv += 1.f - mj.y; o[1] = f2b(lv);
        lv = ((j + 2 == i) ? d : 0.f) - w[q4 * 4 + 2]; lv = mi * mj.z * lv; if (j + 2 == i) lv += 1.f - mj.z; o[2] = f2b(lv);
        lv = ((j + 3 == i) ? d : 0.f) - w[q4 * 4 + 3]; lv = mi * mj.w * lv; if (j + 3 == i) lv += 1.f - mj.w; o[3] = f2b(lv);
        *(ushort4*)(Lo + q4 * 4) = make_ushort4(o[0], o[1], o[2], o[3]);
    }
}

// ---------- fused MFMA GEMM + transpose-pad: yt[(j+4)][C] = (x @ L)^T in bf16 ----------
// grid (N/16, C/32); 4 waves split K 4 ways; CG=2 (L fragment loaded once per k-step).
// MODE 0: bf16 src stride N; MODE 1: f32 src (inline f2b); MODE 2: bf16 stride N/2 repeat;
// MODE 3: x computed on the fly from prev conv's zm/sp/res (fused IN epilogue);
//         block jb==0 writes x f32 (needed as later residual).
template<int MODE>
__global__ __launch_bounds__(256) void k_mmfT(const void* __restrict__ xsrc,
                                              const ushort* __restrict__ Lb,
                                              ushort* __restrict__ yt, int N, int C,
                                              const float* __restrict__ zsrc,
                                              const float2* __restrict__ spst,
                                              const float* __restrict__ resv,
                                              float* __restrict__ xw, int NP) {
    __shared__ float lds[4][64][4];
    __shared__ float smean[32], srs[32];
    int t = threadIdx.x;
    int wv = t >> 6, l = t & 63;
    int lrow = l & 15, lk = l >> 4;
    int j0 = blockIdx.x * 16;
    int c0 = blockIdx.y * 32;

    // zero pad rows (jj<4, jj>=N+4) for this 32-channel tile: 8 rows x 32 ch = 256
    if (blockIdx.x == 0) {
        int row = t >> 5;
        int ch = c0 + (t & 31);
        int jj = (row < 4) ? row : N + row;
        yt[(size_t)jj * C + ch] = 0;
    }

    if (MODE == 3) {
        if (t < 32) {
            int ch = c0 + t;
            const float2* pp = spst + (size_t)ch * NP;
            float s = 0.f, ss = 0.f;
            for (int k = 0; k < NP; k++) { float2 v = pp[k]; s += v.x; ss += v.y; }
            float mean = s / N;
            float var = fmaxf(ss / N - mean * mean, 0.f);
            smean[t] = mean; srs[t] = rsqrtf(var + 1e-5f);
        }
        __syncthreads();
    }

    int kquart = N >> 2;
    size_t kbase = (size_t)wv * kquart + lk * 8;
    const ushort* bp = Lb + (size_t)(j0 + lrow) * N + kbase;
    f32x4 accA = (f32x4){0.f, 0.f, 0.f, 0.f};
    f32x4 accB = (f32x4){0.f, 0.f, 0.f, 0.f};
    if (MODE == 0) {
        const ushort* apA = (const ushort*)xsrc + (size_t)(c0 + lrow) * N + kbase;
        const ushort* apB = (const ushort*)xsrc + (size_t)(c0 + 16 + lrow) * N + kbase;
        for (int k0 = 0; k0 < kquart; k0 += 32) {
            bf16x8 b = *(const bf16x8*)(bp + k0);
            bf16x8 aA = *(const bf16x8*)(apA + k0);
            bf16x8 aB = *(const bf16x8*)(apB + k0);
            accA = __builtin_amdgcn_mfma_f32_16x16x32_bf16(aA, b, accA, 0, 0, 0);
            accB = __builtin_amdgcn_mfma_f32_16x16x32_bf16(aB, b, accB, 0, 0, 0);
        }
    } else if (MODE == 1) {
        const float* apA = (const float*)xsrc + (size_t)(c0 + lrow) * N + kbase;
        const float* apB = (const float*)xsrc + (size_t)(c0 + 16 + lrow) * N + kbase;
        for (int k0 = 0; k0 < kquart; k0 += 32) {
            bf16x8 b = *(const bf16x8*)(bp + k0);
            float4 f0 = *(const float4*)(apA + k0);
            float4 f1 = *(const float4*)(apA + k0 + 4);
            bf16x8 aA;
            aA[0] = (short)f2b(f0.x); aA[1] = (short)f2b(f0.y);
            aA[2] = (short)f2b(f0.z); aA[3] = (short)f2b(f0.w);
            aA[4] = (short)f2b(f1.x); aA[5] = (short)f2b(f1.y);
            aA[6] = (short)f2b(f1.z); aA[7] = (short)f2b(f1.w);
            float4 g0 = *(const float4*)(apB + k0);
            float4 g1 = *(const float4*)(apB + k0 + 4);
            bf16x8 aB;
            aB[0] = (short)f2b(g0.x); aB[1] = (short)f2b(g0.y);
            aB[2] = (short)f2b(g0.z); aB[3] = (short)f2b(g0.w);
            aB[4] = (short)f2b(g1.x); aB[5] = (short)f2b(g1.y);
            aB[6] = (short)f2b(g1.z); aB[7] = (short)f2b(g1.w);
            accA = __builtin_amdgcn_mfma_f32_16x16x32_bf16(aA, b, accA, 0, 0, 0);
            accB = __builtin_amdgcn_mfma_f32_16x16x32_bf16(aB, b, accB, 0, 0, 0);
        }
    } else if (MODE == 2) {
        const ushort* apA = (const ushort*)xsrc + (size_t)(c0 + lrow) * (N >> 1) + (kbase >> 1);
        const ushort* apB = (const ushort*)xsrc + (size_t)(c0 + 16 + lrow) * (N >> 1) + (kbase >> 1);
        for (int k0 = 0; k0 < kquart; k0 += 32) {
            bf16x8 b = *(const bf16x8*)(bp + k0);
            ushort4 v = *(const ushort4*)(apA + (k0 >> 1));
            bf16x8 aA;
            aA[0] = (short)v.x; aA[1] = (short)v.x;
            aA[2] = (short)v.y; aA[3] = (short)v.y;
            aA[4] = (short)v.z; aA[5] = (short)v.z;
            aA[6] = (short)v.w; aA[7] = (short)v.w;
            ushort4 u = *(const ushort4*)(apB + (k0 >> 1));
            bf16x8 aB;
            aB[0] = (short)u.x; aB[1] = (short)u.x;
            aB[2] = (short)u.y; aB[3] = (short)u.y;
            aB[4] = (short)u.z; aB[5] = (short)u.z;
            aB[6] = (short)u.w; aB[7] = (short)u.w;
            accA = __builtin_amdgcn_mfma_f32_16x16x32_bf16(aA, b, accA, 0, 0, 0);
            accB = __builtin_amdgcn_mfma_f32_16x16x32_bf16(aB, b, accB, 0, 0, 0);
        }
    } else {
        // MODE 3: x = relu((z - mean) * rs) + res, on the fly
        float meanA = smean[lrow], rsAv = srs[lrow];
        float meanB = smean[16 + lrow], rsBv = srs[16 + lrow];
        const float* zA = zsrc + (size_t)(c0 + lrow) * N + kbase;
        const float* zB = zsrc + (size_t)(c0 + 16 + lrow) * N + kbase;
        const float* rA = resv + (size_t)(c0 + lrow) * N + kbase;
        const float* rB = resv + (size_t)(c0 + 16 + lrow) * N + kbase;
        float* wA = xw + (size_t)(c0 + lrow) * N + kbase;
        float* wB = xw + (size_t)(c0 + 16 + lrow) * N + kbase;
        bool wr = (blockIdx.x == 0);
        for (int k0 = 0; k0 < kquart; k0 += 32) {
            bf16x8 b = *(const bf16x8*)(bp + k0);
            float4 z0 = *(const float4*)(zA + k0);
            float4 z1 = *(const float4*)(zA + k0 + 4);
            float4 r0 = *(const float4*)(rA + k0);
            float4 r1 = *(const float4*)(rA + k0 + 4);
            float4 xa0, xa1;
            xa0.x = fmaxf((z0.x - meanA) * rsAv, 0.f) + r0.x;
            xa0.y = fmaxf((z0.y - meanA) * rsAv, 0.f) + r0.y;
            xa0.z = fmaxf((z0.z - meanA) * rsAv, 0.f) + r0.z;
            xa0.w = fmaxf((z0.w - meanA) * rsAv, 0.f) + r0.w;
            xa1.x = fmaxf((z1.x - meanA) * rsAv, 0.f) + r1.x;
            xa1.y = fmaxf((z1.y - meanA) * rsAv, 0.f) + r1.y;
            xa1.z = fmaxf((z1.z - meanA) * rsAv, 0.f) + r1.z;
            xa1.w = fmaxf((z1.w - meanA) * rsAv, 0.f) + r1.w;
            if (wr) { *(float4*)(wA + k0) = xa0; *(float4*)(wA + k0 + 4) = xa1; }
            bf16x8 aA;
            aA[0] = (short)f2b(xa0.x); aA[1] = (short)f2b(xa0.y);
            aA[2] = (short)f2b(xa0.z); aA[3] = (short)f2b(xa0.w);
            aA[4] = (short)f2b(xa1.x); aA[5] = (short)f2b(xa1.y);
            aA[6] = (short)f2b(xa1.z); aA[7] = (short)f2b(xa1.w);
            float4 u0 = *(const float4*)(zB + k0);
            float4 u1 = *(const float4*)(zB + k0 + 4);
            float4 s0 = *(const float4*)(rB + k0);
            float4 s1 = *(const float4*)(rB + k0 + 4);
            float4 xb0, xb1;
            xb0.x = fmaxf((u0.x - meanB) * rsBv, 0.f) + s0.x;
            xb0.y = fmaxf((u0.y - meanB) * rsBv, 0.f) + s0.y;
            xb0.z = fmaxf((u0.z - meanB) * rsBv, 0.f) + s0.z;
            xb0.w = fmaxf((u0.w - meanB) * rsBv, 0.f) + s0.w;
            xb1.x = fmaxf((u1.x - meanB) * rsBv, 0.f) + s1.x;
            xb1.y = fmaxf((u1.y - meanB) * rsBv, 0.f) + s1.y;
            xb1.z = fmaxf((u1.z - meanB) * rsBv, 0.f) + s1.z;
            xb1.w = fmaxf((u1.w - meanB) * rsBv, 0.f) + s1.w;
            if (wr) { *(float4*)(wB + k0) = xb0; *(float4*)(wB + k0 + 4) = xb1; }
            bf16x8 aB;
            aB[0] = (short)f2b(xb0.x); aB[1] = (short)f2b(xb0.y);
            aB[2] = (short)f2b(xb0.z); aB[3] = (short)f2b(xb0.w);
            aB[4] = (short)f2b(xb1.x); aB[5] = (short)f2b(xb1.y);
            aB[6] = (short)f2b(xb1.z); aB[7] = (short)f2b(xb1.w);
            accA = __builtin_amdgcn_mfma_f32_16x16x32_bf16(aA, b, accA, 0, 0, 0);
            accB = __builtin_amdgcn_mfma_f32_16x16x32_bf16(aB, b, accB, 0, 0, 0);
        }
    }
    #pragma unroll
    for (int g = 0; g < 2; g++) {
        #pragma unroll
        for (int r = 0; r < 4; r++) lds[wv][l][r] = (g == 0) ? accA[r] : accB[r];
        __syncthreads();
        if (t < 64) {
            int gg = t >> 4, j16 = t & 15;
            float s0 = lds[0][t][0] + lds[1][t][0] + lds[2][t][0] + lds[3][t][0];
            float s1 = lds[0][t][1] + lds[1][t][1] + lds[2][t][1] + lds[3][t][1];
            float s2 = lds[0][t][2] + lds[1][t][2] + lds[2][t][2] + lds[3][t][2];
            float s3 = lds[0][t][3] + lds[1][t][3] + lds[2][t][3] + lds[3][t][3];
            *(ushort4*)(yt + (size_t)(j0 + j16 + 4) * C + c0 + g * 16 + gg * 4) =
                make_ushort4(f2b(s0), f2b(s1), f2b(s2), f2b(s3));
        }
        __syncthreads();
    }
}

// ---------- weight prep: tap-major bf16 matrices, fwd + transpose orientations ----------
struct WMeta {
    const float* src[11];
    unsigned long long off_f[11];
    unsigned long long off_t[11];
    int ca[11];
    int cb[11];
};

__global__ __launch_bounds__(256) void k_wprep(WMeta meta, ushort* __restrict__ Wm) {
    int which = blockIdx.y;
    int a = meta.ca[which], b = meta.cb[which];
    int tot = a * b * 9;
    int idx = blockIdx.x * 256 + threadIdx.x;
    if (idx >= tot) return;
    int t = idx % 9;
    int oi = idx / 9;
    int i = oi % b;
    int o = oi / b;
    ushort h = f2b(meta.src[which][idx]);   // K[o][i][t]
    Wm[meta.off_f[which] + ((size_t)t * a + o) * b + i] = h;
    Wm[meta.off_t[which] + ((size_t)(8 - t) * b + i) * a + o] = h;
}

// ---------- conv via MFMA, PG=2 p-tiles/block (Wm fragment loaded once) ----------
// grid (N/32, C_out/16); fused mask + per-block IN stat partials (NP = N/32).
__global__ __launch_bounds__(256) void k_convM(const ushort* __restrict__ yt,
                                               const ushort* __restrict__ Wm,
                                               float* __restrict__ zm,
                                               const float* __restrict__ m,
                                               float2* __restrict__ sp,
                                               int C_in, int C_out, int N,
                                               int iters, int NP) {
    __shared__ float lds[4][64][4];
    int t = threadIdx.x;
    int wv = t >> 6, l = t & 63;
    int prow = l & 15, kq = l >> 4;
    int p00 = blockIdx.x * 32;
    int o0 = blockIdx.y * 16;
    int per = (iters + 3) >> 2;
    int it0 = wv * per;
    int it1 = min(iters, it0 + per);
    f32x4 accA = (f32x4){0.f, 0.f, 0.f, 0.f};
    f32x4 accB = (f32x4){0.f, 0.f, 0.f, 0.f};
    for (int it = it0; it < it1; it++) {
        int ks = it / 9;
        int tp = it - ks * 9;
        int kb = ks * 32 + kq * 8;
        bf16x8 a = *(const bf16x8*)(Wm + ((size_t)tp * C_out + o0 + prow) * C_in + kb);
        bf16x8 bA = *(const bf16x8*)(yt + (size_t)(p00 + prow + tp) * C_in + kb);
        bf16x8 bB = *(const bf16x8*)(yt + (size_t)(p00 + 16 + prow + tp) * C_in + kb);
        accA = __builtin_amdgcn_mfma_f32_16x16x32_bf16(a, bA, accA, 0, 0, 0);
        accB = __builtin_amdgcn_mfma_f32_16x16x32_bf16(a, bB, accB, 0, 0, 0);
    }
    float stsum[4] = {0.f, 0.f, 0.f, 0.f}, stss[4] = {0.f, 0.f, 0.f, 0.f};
    #pragma unroll
    for (int pg = 0; pg < 2; pg++) {
        int p0 = p00 + pg * 16;
        #pragma unroll
        for (int r = 0; r < 4; r++) lds[wv][l][r] = (pg == 0) ? accA[r] : accB[r];
        __syncthreads();
        if (t < 64) {
            int g = t >> 4, j16 = t & 15;
            int j = p0 + j16;
            float mj = m[j];
            #pragma unroll
            for (int r = 0; r < 4; r++) {
                float z = lds[0][t][r] + lds[1][t][r] + lds[2][t][r] + lds[3][t][r];
                z *= mj;
                zm[(size_t)(o0 + g * 4 + r) * N + j] = z;
                float zs = z, zz = z * z;
                #pragma unroll
                for (int mask = 1; mask < 16; mask <<= 1) {
                    zs += __shfl_xor(zs, mask);
                    zz += __shfl_xor(zz, mask);
                }
                stsum[r] += zs; stss[r] += zz;
            }
        }
        __syncthreads();
    }
    if (t < 64 && (t & 15) == 0) {
        int g = t >> 4;
        #pragma unroll
        for (int r = 0; r < 4; r++)
            sp[(size_t)(o0 + g * 4 + r) * NP + blockIdx.x] = make_float2(stsum[r], stss[r]);
    }
}

// ---------- conv epilogue: global stats from NP partials + IN apply + relu + residual ----------
__global__ __launch_bounds__(256) void k_convC2(const float* __restrict__ zm,
                                                const float2* __restrict__ sp,
                                                const float* __restrict__ res,
                                                float* __restrict__ xout,
                                                ushort* __restrict__ xob, int N, int NP) {
    int o = blockIdx.y;
    int t = threadIdx.x;
    float2 pp = (t < NP) ? sp[(size_t)o * NP + t] : make_float2(0.f, 0.f);
    __shared__ float red[256], red2[256];
    red[t] = pp.x; red2[t] = pp.y;
    __syncthreads();
    for (int off = 128; off > 0; off >>= 1) {
        if (t < off) { red[t] += red[t + off]; red2[t] += red2[t + off]; }
        __syncthreads();
    }
    float mean = red[0] / N;
    float var = fmaxf(red2[0] / N - mean * mean, 0.f);
    float rs = rsqrtf(var + 1e-5f);
    int base = blockIdx.x * 512 + t * 2;
    float2 z = *(const float2*)(zm + (size_t)o * N + base);
    float v0 = fmaxf((z.x - mean) * rs, 0.f);
    float v1 = fmaxf((z.y - mean) * rs, 0.f);
    if (res) {
        float2 r = *(const float2*)(res + (size_t)o * N + base);
        v0 += r.x; v1 += r.y;
    }
    *(float2*)(xout + (size_t)o * N + base) = make_float2(v0, v1);
    if (xob) *(ushort2*)(xob + (size_t)o * N + base) = make_ushort2(f2b(v0), f2b(v1));
}

// ---------- fused pool (z rows + mask + X), z dual-written bf16 ----------
__global__ __launch_bounds__(256) void k_poolall(const float* __restrict__ z_in,
                                                 float* __restrict__ z_out,
                                                 ushort* __restrict__ zb_out, int Cz,
                                                 const float* __restrict__ m_in, float* __restrict__ m_out,
                                                 const float* __restrict__ X_in, float* __restrict__ X_out, int Nin) {
    int No = Nin >> 1;
    int idx = blockIdx.x * 256 + threadIdx.x;
    int total = (Cz + 4) * No;
    if (idx >= total) return;
    int r = idx / No, ii = idx - r * No;
    const float* src;
    if (r < Cz) {
        src = z_in + (size_t)r * Nin;
        float a = (ii > 0) ? src[2 * ii - 1] : 0.f;
        float v = (a + src[2 * ii] + src[2 * ii + 1]) * (1.f / 3.f);
        z_out[(size_t)r * No + ii] = v;
        zb_out[(size_t)r * No + ii] = f2b(v);
    } else if (r == Cz) {
        src = m_in;
        float a = (ii > 0) ? src[2 * ii - 1] : 0.f;
        m_out[ii] = (a + src[2 * ii] + src[2 * ii + 1]) * (1.f / 3.f);
    } else {
        src = X_in + (size_t)(r - Cz - 1) * Nin;
        float a = (ii > 0) ? src[2 * ii - 1] : 0.f;
        X_out[(size_t)(r - Cz - 1) * No + ii] = (a + src[2 * ii] + src[2 * ii + 1]) * (1.f / 3.f);
    }
}

// ---------- host ----------

extern "C" void kernel_launch(void* const* d_in, const int* in_sizes, int n_in,
                              void* d_out, int out_size, void* d_ws, size_t ws_size,
                              hipStream_t stream) {
    (void)in_sizes; (void)n_in; (void)out_size; (void)ws_size;
    const float* x_in = (const float*)d_in[0];
    const float* X0 = (const float*)d_in[1];
    const float* m0 = (const float*)d_in[2];
    const float* Kw[11];
    for (int i = 0; i < 11; i++) Kw[i] = (const float*)d_in[3 + i];
    float* out = (float*)d_out;
    float* ws = (float*)d_ws;

    const int Ns[4] = {4096, 2048, 1024, 512};
    const int KA[11] = {32, 32, 64, 64, 64, 128, 128, 128, 256, 256, 256};
    const int KB[11] = {32, 32, 32, 64, 64, 64, 128, 128, 128, 256, 256};

    size_t off = 0;
    auto alloc = [&](size_t n) { float* p = ws + off; off += (n + 63) & ~(size_t)63; return p; };
    ushort* Lb[4];
    Lb[0] = (ushort*)alloc(8388608); Lb[1] = (ushort*)alloc(2097152);
    Lb[2] = (ushort*)alloc(524288);  Lb[3] = (ushort*)alloc(131072);
    float* Xnb = alloc(3 * 4096);
    float* sqb = alloc(4096);
    float* spbuf = alloc(32768);
    float* zmbuf = alloc(262144);
    float* mlev[4];
    mlev[0] = const_cast<float*>(m0);
    mlev[1] = alloc(2048); mlev[2] = alloc(1024); mlev[3] = alloc(512);
    float* Xlev[4];
    Xlev[0] = const_cast<float*>(X0);
    Xlev[1] = alloc(3 * 2048); Xlev[2] = alloc(3 * 1024); Xlev[3] = alloc(3 * 512);
    float* pA[4], *pB[4], *xs[3];
    for (int l = 0; l < 4; l++) { pA[l] = alloc(131072); pB[l] = alloc(131072); }
    for (int l = 0; l < 3; l++) xs[l] = alloc(131072);
    float* zbig = alloc(262144);
    ushort* pAb[4], *pBb[4], *xsb[3];
    for (int l = 0; l < 4; l++) { pAb[l] = (ushort*)alloc(65536); pBb[l] = (ushort*)alloc(65536); }
    for (int l = 0; l < 3; l++) xsb[l] = (ushort*)alloc(65536);
    ushort* ytb = (ushort*)alloc(140000);
    ushort* Wm = (ushort*)alloc(1960000);

    size_t woff_f[11], woff_t[11];
    {
        size_t acc = 0;
        for (int k = 0; k < 11; k++) { woff_f[k] = acc; acc += (size_t)KA[k] * KB[k] * 9; }
        for (int k = 0; k < 11; k++) { woff_t[k] = acc; acc += (size_t)KA[k] * KB[k] * 9; }
    }

    {
        WMeta meta;
        for (int k = 0; k < 11; k++) {
            meta.src[k] = Kw[k];
            meta.off_f[k] = woff_f[k];
            meta.off_t[k] = woff_t[k];
            meta.ca[k] = KA[k];
            meta.cb[k] = KB[k];
        }
        k_wprep<<<dim3(2304, 11), 256, 0, stream>>>(meta, Wm);
    }

    auto build_lap = [&](int lvl) {
        int N = Ns[lvl];
        k_prep<<<1, 256, 0, stream>>>(Xlev[lvl], Xnb, sqb, N);
        if (N == 4096)      k_lap<16><<<N, 256, 0, stream>>>(Xnb, sqb, mlev[lvl], Lb[lvl], N);
        else if (N == 2048) k_lap<8><<<N, 256, 0, stream>>>(Xnb, sqb, mlev[lvl], Lb[lvl], N);
        else if (N == 1024) k_lap<4><<<N, 256, 0, stream>>>(Xnb, sqb, mlev[lvl], Lb[lvl], N);
        else                k_lap<4><<<N, 128, 0, stream>>>(Xnb, sqb, mlev[lvl], Lb[lvl], N);
    };

    // mode 0: bf16 src; mode 1: f32 src; mode 2: bf16 half-N repeat src
    auto matmul = [&](const void* xsrc, int C, int lvl, int mode) {
        int N = Ns[lvl];
        dim3 g(N / 16, C / 32);
        if (mode == 0)      k_mmfT<0><<<g, 256, 0, stream>>>(xsrc, Lb[lvl], ytb, N, C, nullptr, nullptr, nullptr, nullptr, 0);
        else if (mode == 1) k_mmfT<1><<<g, 256, 0, stream>>>(xsrc, Lb[lvl], ytb, N, C, nullptr, nullptr, nullptr, nullptr, 0);
        else                k_mmfT<2><<<g, 256, 0, stream>>>(xsrc, Lb[lvl], ytb, N, C, nullptr, nullptr, nullptr, nullptr, 0);
    };

    // mode 3: A from prev conv's zm/sp + res; jb==0 writes x f32 to xw
    auto matmul3 = [&](const float* resv, float* xw, int C, int lvl) {
        int N = Ns[lvl];
        int NP = N / 32;
        dim3 g(N / 16, C / 32);
        k_mmfT<3><<<g, 256, 0, stream>>>(nullptr, Lb[lvl], ytb, N, C,
                                         zmbuf, (const float2*)spbuf, resv, xw, NP);
    };

    // conv: MFMA conv + optional epilogue dispatch
    auto conv = [&](int kidx, int lvl, const float* resv, float* ov, ushort* ovb,
                    int Cin, int Cout, int tr, bool doC2) {
        int N = Ns[lvl];
        int iters = (Cin / 32) * 9;
        int NP = N / 32;
        const ushort* wm = Wm + (tr ? woff_t[kidx] : woff_f[kidx]);
        k_convM<<<dim3(N / 32, Cout / 16), 256, 0, stream>>>(ytb, wm, zmbuf, mlev[lvl],
                                                             (float2*)spbuf, Cin, Cout, N, iters, NP);
        if (doC2) {
            int NBs = N / 512;
            k_convC2<<<dim3(NBs, Cout), 256, 0, stream>>>(zmbuf, (const float2*)spbuf, resv, ov, ovb, N, NP);
        }
    };

    auto poolall = [&](const float* z_in, float* z_out, ushort* zb_out, int Cz, int lvl_from) {
        int Nin = Ns[lvl_from];
        int No = Nin >> 1;
        int total = (Cz + 4) * No;
        k_poolall<<<(total + 255) / 256, 256, 0, stream>>>(z_in, z_out, zb_out, Cz,
                                                           mlev[lvl_from], mlev[lvl_from + 1],
                                                           Xlev[lvl_from], Xlev[lvl_from + 1], Nin);
    };

    // ---- down ----
    build_lap(0);
    matmul(x_in, 32, 0, 1);    conv(0, 0, x_in, pA[0], pAb[0], 32, 32, 0, true);
    matmul(pAb[0], 32, 0, 0);  conv(1, 0, pA[0], xs[0], xsb[0], 32, 32, 0, true);
    matmul(xsb[0], 32, 0, 0);  conv(2, 0, nullptr, zbig, nullptr, 32, 64, 0, true);
    poolall(zbig, pA[1], pAb[1], 64, 0);
    build_lap(1);
    matmul(pAb[1], 64, 1, 0);        conv(3, 1, nullptr, nullptr, nullptr, 64, 64, 0, false);
    matmul3(pA[1], pB[1], 64, 1);    conv(4, 1, nullptr, nullptr, nullptr, 64, 64, 0, false);
    matmul3(pB[1], xs[1], 64, 1);    conv(5, 1, nullptr, zbig, nullptr, 64, 128, 0, true);
    poolall(zbig, pA[2], pAb[2], 128, 1);
    build_lap(2);
    matmul(pAb[2], 128, 2, 0);       conv(6, 2, nullptr, nullptr, nullptr, 128, 128, 0, false);
    matmul3(pA[2], pB[2], 128, 2);   conv(7, 2, nullptr, nullptr, nullptr, 128, 128, 0, false);
    matmul3(pB[2], xs[2], 128, 2);   conv(8, 2, nullptr, zbig, nullptr, 128, 256, 0, true);
    poolall(zbig, pA[3], pAb[3], 256, 2);
    build_lap(3);
    matmul(pAb[3], 256, 3, 0);       conv(9, 3, nullptr, nullptr, nullptr, 256, 256, 0, false);
    matmul3(pA[3], pB[3], 256, 3);   conv(10, 3, nullptr, nullptr, nullptr, 256, 256, 0, false);

    // ---- up ----
    matmul3(pB[3], pA[3], 256, 3);   conv(10, 3, nullptr, nullptr, nullptr, 256, 256, 1, false);
    matmul3(pA[3], pB[3], 256, 3);   conv(9, 3, pB[3], pA[3], pAb[3], 256, 256, 1, true);

    matmul(pAb[3], 256, 2, 2);       conv(8, 2, nullptr, nullptr, nullptr, 256, 128, 1, false);
    matmul3(xs[2], pB[2], 128, 2);   conv(7, 2, nullptr, nullptr, nullptr, 128, 128, 1, false);
    matmul3(pB[2], pA[2], 128, 2);   conv(6, 2, pA[2], pB[2], pBb[2], 128, 128, 1, true);

    matmul(pBb[2], 128, 1, 2);       conv(5, 1, nullptr, nullptr, nullptr, 128, 64, 1, false);
    matmul3(xs[1], pA[1], 64, 1);    conv(4, 1, nullptr, nullptr, nullptr, 64, 64, 1, false);
    matmul3(pA[1], pB[1], 64, 1);    conv(3, 1, pB[1], pA[1], pAb[1], 64, 64, 1, true);

    matmul(pAb[1], 64, 0, 2);        conv(2, 0, xs[0], pB[0], pBb[0], 64, 32, 1, true);
    matmul(pBb[0], 32, 0, 0);        conv(1, 0, pB[0], pA[0], pAb[0], 32, 32, 1, true);
    matmul(pAb[0], 32, 0, 0);        conv(0, 0, pA[0], out, nullptr, 32, 32, 1, true);
}

// Round 20
// 505.837 us; speedup vs baseline: 1.2120x; 1.2120x over previous
//
#include <hip/hip_runtime.h>
#include <math.h>

typedef __attribute__((ext_vector_type(8))) short bf16x8;
typedef __attribute__((ext_vector_type(4))) float f32x4;

__device__ __forceinline__ ushort f2b(float f) {
    union { float f; unsigned u; } v; v.f = f;
    unsigned r = (v.u + 0x7FFFu + ((v.u >> 16) & 1u)) >> 16;
    return (ushort)r;
}
__device__ __forceinline__ float b2f(ushort h) {
    union { unsigned u; float f; } v; v.u = ((unsigned)h) << 16;
    return v.f;
}

// ---------- Laplacian pipeline ----------

// single block: row stats (ddof=1) for 3 rows kept in LDS, then Xn/sq write
__global__ __launch_bounds__(256) void k_prep(const float* __restrict__ X,
                                              float* __restrict__ Xn,
                                              float* __restrict__ sq, int N) {
    __shared__ double sh_s[256], sh_ss[256];
    __shared__ float sst[3];
    int t = threadIdx.x;
    for (int r = 0; r < 3; r++) {
        const float* row = X + (size_t)r * N;
        double s = 0.0, ss = 0.0;
        for (int i = t * 4; i < N; i += 1024) {
            float4 v = *(const float4*)(row + i);
            s += (double)v.x + (double)v.y + (double)v.z + (double)v.w;
            ss += (double)v.x * v.x + (double)v.y * v.y + (double)v.z * v.z + (double)v.w * v.w;
        }
        sh_s[t] = s; sh_ss[t] = ss; __syncthreads();
        for (int off = 128; off > 0; off >>= 1) {
            if (t < off) { sh_s[t] += sh_s[t + off]; sh_ss[t] += sh_ss[t + off]; }
            __syncthreads();
        }
        if (t == 0) {
            double mean = sh_s[0] / N;
            double var = (sh_ss[0] - mean * sh_s[0]) / (N - 1);
            if (var < 0.0) var = 0.0;
            sst[r] = 1.0f / ((float)sqrt(var) + 0.01f);
        }
        __syncthreads();
    }
    float s0 = sst[0], s1 = sst[1], s2 = sst[2];
    for (int i = t * 4; i < N; i += 1024) {
        float4 v0 = *(const float4*)(X + i);
        float4 v1 = *(const float4*)(X + N + i);
        float4 v2 = *(const float4*)(X + 2 * N + i);
        v0.x *= s0; v0.y *= s0; v0.z *= s0; v0.w *= s0;
        v1.x *= s1; v1.y *= s1; v1.z *= s1; v1.w *= s1;
        v2.x *= s2; v2.y *= s2; v2.z *= s2; v2.w *= s2;
        *(float4*)(Xn + i) = v0;
        *(float4*)(Xn + N + i) = v1;
        *(float4*)(Xn + 2 * N + i) = v2;
        float4 sv;
        sv.x = v0.x * v0.x + v1.x * v1.x + v2.x * v2.x;
        sv.y = v0.y * v0.y + v1.y * v1.y + v2.y * v2.y;
        sv.z = v0.z * v0.z + v1.z * v1.z + v2.z * v2.z;
        sv.w = v0.w * v0.w + v1.w * v1.w + v2.w * v2.w;
        *(float4*)(sq + i) = sv;
    }
}

// one block per row i: W row from vectorized Xn/sq, row-sum in-block, finalize, write bf16 L
template<int CPT>
__global__ __launch_bounds__(256) void k_lap(const float* __restrict__ Xn,
                                             const float* __restrict__ sq,
                                             const float* __restrict__ m,
                                             ushort* __restrict__ L, int N) {
    int i = blockIdx.x;
    int t = threadIdx.x;
    int T = blockDim.x;
    float a0 = Xn[i], a1 = Xn[N + i], a2 = Xn[2 * N + i];
    float si = sq[i];
    int j0 = t * CPT;
    float w[CPT];
    float psum = 0.f;
    #pragma unroll
    for (int q4 = 0; q4 < CPT / 4; q4++) {
        int j = j0 + q4 * 4;
        float4 x0 = *(const float4*)(Xn + j);
        float4 x1 = *(const float4*)(Xn + N + j);
        float4 x2 = *(const float4*)(Xn + 2 * N + j);
        float4 sv = *(const float4*)(sq + j);
        float D;
        D = fmaxf(si + sv.x - 2.f * (a0 * x0.x + a1 * x1.x + a2 * x2.x), 0.f);
        w[q4 * 4 + 0] = exp2f(-D * 0.14426950408889634f);
        D = fmaxf(si + sv.y - 2.f * (a0 * x0.y + a1 * x1.y + a2 * x2.y), 0.f);
        w[q4 * 4 + 1] = exp2f(-D * 0.14426950408889634f);
        D = fmaxf(si + sv.z - 2.f * (a0 * x0.z + a1 * x1.z + a2 * x2.z), 0.f);
        w[q4 * 4 + 2] = exp2f(-D * 0.14426950408889634f);
        D = fmaxf(si + sv.w - 2.f * (a0 * x0.w + a1 * x1.w + a2 * x2.w), 0.f);
        w[q4 * 4 + 3] = exp2f(-D * 0.14426950408889634f);
        psum += w[q4 * 4] + w[q4 * 4 + 1] + w[q4 * 4 + 2] + w[q4 * 4 + 3];
    }
    __shared__ float red[256];
    red[t] = psum; __syncthreads();
    for (int off = T >> 1; off > 0; off >>= 1) {
        if (t < off) red[t] += red[t + off];
        __syncthreads();
    }
    float d = red[0];
    float mi = m[i];
    ushort* Lo = L + (size_t)i * N + j0;
    #pragma unroll
    for (int q4 = 0; q4 < CPT / 4; q4++) {
        int j = j0 + q4 * 4;
        float4 mj = *(const float4*)(m + j);
        ushort o[4];
        float lv;
        lv = ((j + 0 == i) ? d : 0.f) - w[q4 * 4 + 0]; lv = mi * mj.x * lv; if (j + 0 == i) lv += 1.f - mj.x; o[0] = f2b(lv);
        lv = ((j + 1 == i) ? d : 0.f) - w[q4 * 4 + 1]; lv = mi * mj.y * lv; if (j + 1 == i) lv += 1.f - mj.y; o[1] = f2b(lv);
        lv = ((j + 2 == i) ? d : 0.f) - w[q4 * 4 + 2]; lv = mi * mj.z * lv; if (j + 2 == i) lv += 1.f - mj.z; o[2] = f2b(lv);
        lv = ((j + 3 == i) ? d : 0.f) - w[q4 * 4 + 3]; lv = mi * mj.w * lv; if (j + 3 == i) lv += 1.f - mj.w; o[3] = f2b(lv);
        *(ushort4*)(Lo + q4 * 4) = make_ushort4(o[0], o[1], o[2], o[3]);
    }
}

// ---------- fused MFMA GEMM + transpose-pad: yt[(j+4)][C] = (x @ L)^T in bf16 ----------
// grid (N/16, C/32); 4 waves split K 4 ways; each block does 32 channels (CG=2):
// the L b-fragment is loaded ONCE per k-step and reused for both 16-channel tiles.
// MODE 0: bf16 src stride N; MODE 1: f32 src (inline f2b); MODE 2: bf16 src stride N/2 repeat.
template<int MODE>
__global__ __launch_bounds__(256) void k_mmfT(const void* __restrict__ xsrc,
                                              const ushort* __restrict__ Lb,
                                              ushort* __restrict__ yt, int N, int C) {
    __shared__ float lds[4][64][4];
    int t = threadIdx.x;
    int wv = t >> 6, l = t & 63;
    int lrow = l & 15, lk = l >> 4;
    int j0 = blockIdx.x * 16;
    int c0 = blockIdx.y * 32;

    // zero pad rows (jj<4, jj>=N+4) for this 32-channel tile: 8 rows x 32 ch = 256
    if (blockIdx.x == 0) {
        int row = t >> 5;
        int ch = c0 + (t & 31);
        int jj = (row < 4) ? row : N + row;
        yt[(size_t)jj * C + ch] = 0;
    }

    int kquart = N >> 2;
    size_t kbase = (size_t)wv * kquart + lk * 8;
    const ushort* bp = Lb + (size_t)(j0 + lrow) * N + kbase;
    f32x4 accA = (f32x4){0.f, 0.f, 0.f, 0.f};
    f32x4 accB = (f32x4){0.f, 0.f, 0.f, 0.f};
    if (MODE == 0) {
        const ushort* apA = (const ushort*)xsrc + (size_t)(c0 + lrow) * N + kbase;
        const ushort* apB = (const ushort*)xsrc + (size_t)(c0 + 16 + lrow) * N + kbase;
        for (int k0 = 0; k0 < kquart; k0 += 32) {
            bf16x8 b = *(const bf16x8*)(bp + k0);
            bf16x8 aA = *(const bf16x8*)(apA + k0);
            bf16x8 aB = *(const bf16x8*)(apB + k0);
            accA = __builtin_amdgcn_mfma_f32_16x16x32_bf16(aA, b, accA, 0, 0, 0);
            accB = __builtin_amdgcn_mfma_f32_16x16x32_bf16(aB, b, accB, 0, 0, 0);
        }
    } else if (MODE == 1) {
        const float* apA = (const float*)xsrc + (size_t)(c0 + lrow) * N + kbase;
        const float* apB = (const float*)xsrc + (size_t)(c0 + 16 + lrow) * N + kbase;
        for (int k0 = 0; k0 < kquart; k0 += 32) {
            bf16x8 b = *(const bf16x8*)(bp + k0);
            float4 f0 = *(const float4*)(apA + k0);
            float4 f1 = *(const float4*)(apA + k0 + 4);
            bf16x8 aA;
            aA[0] = (short)f2b(f0.x); aA[1] = (short)f2b(f0.y);
            aA[2] = (short)f2b(f0.z); aA[3] = (short)f2b(f0.w);
            aA[4] = (short)f2b(f1.x); aA[5] = (short)f2b(f1.y);
            aA[6] = (short)f2b(f1.z); aA[7] = (short)f2b(f1.w);
            float4 g0 = *(const float4*)(apB + k0);
            float4 g1 = *(const float4*)(apB + k0 + 4);
            bf16x8 aB;
            aB[0] = (short)f2b(g0.x); aB[1] = (short)f2b(g0.y);
            aB[2] = (short)f2b(g0.z); aB[3] = (short)f2b(g0.w);
            aB[4] = (short)f2b(g1.x); aB[5] = (short)f2b(g1.y);
            aB[6] = (short)f2b(g1.z); aB[7] = (short)f2b(g1.w);
            accA = __builtin_amdgcn_mfma_f32_16x16x32_bf16(aA, b, accA, 0, 0, 0);
            accB = __builtin_amdgcn_mfma_f32_16x16x32_bf16(aB, b, accB, 0, 0, 0);
        }
    } else {
        const ushort* apA = (const ushort*)xsrc + (size_t)(c0 + lrow) * (N >> 1) + (kbase >> 1);
        const ushort* apB = (const ushort*)xsrc + (size_t)(c0 + 16 + lrow) * (N >> 1) + (kbase >> 1);
        for (int k0 = 0; k0 < kquart; k0 += 32) {
            bf16x8 b = *(const bf16x8*)(bp + k0);
            ushort4 v = *(const ushort4*)(apA + (k0 >> 1));
            bf16x8 aA;
            aA[0] = (short)v.x; aA[1] = (short)v.x;
            aA[2] = (short)v.y; aA[3] = (short)v.y;
            aA[4] = (short)v.z; aA[5] = (short)v.z;
            aA[6] = (short)v.w; aA[7] = (short)v.w;
            ushort4 u = *(const ushort4*)(apB + (k0 >> 1));
            bf16x8 aB;
            aB[0] = (short)u.x; aB[1] = (short)u.x;
            aB[2] = (short)u.y; aB[3] = (short)u.y;
            aB[4] = (short)u.z; aB[5] = (short)u.z;
            aB[6] = (short)u.w; aB[7] = (short)u.w;
            accA = __builtin_amdgcn_mfma_f32_16x16x32_bf16(aA, b, accA, 0, 0, 0);
            accB = __builtin_amdgcn_mfma_f32_16x16x32_bf16(aB, b, accB, 0, 0, 0);
        }
    }
    #pragma unroll
    for (int g = 0; g < 2; g++) {
        #pragma unroll
        for (int r = 0; r < 4; r++) lds[wv][l][r] = (g == 0) ? accA[r] : accB[r];
        __syncthreads();
        if (t < 64) {
            int gg = t >> 4, j16 = t & 15;
            float s0 = lds[0][t][0] + lds[1][t][0] + lds[2][t][0] + lds[3][t][0];
            float s1 = lds[0][t][1] + lds[1][t][1] + lds[2][t][1] + lds[3][t][1];
            float s2 = lds[0][t][2] + lds[1][t][2] + lds[2][t][2] + lds[3][t][2];
            float s3 = lds[0][t][3] + lds[1][t][3] + lds[2][t][3] + lds[3][t][3];
            *(ushort4*)(yt + (size_t)(j0 + j16 + 4) * C + c0 + g * 16 + gg * 4) =
                make_ushort4(f2b(s0), f2b(s1), f2b(s2), f2b(s3));
        }
        __syncthreads();
    }
}

// ---------- weight prep: tap-major bf16 matrices, fwd + transpose orientations ----------
struct WMeta {
    const float* src[11];
    unsigned long long off_f[11];
    unsigned long long off_t[11];
    int ca[11];
    int cb[11];
};

__global__ __launch_bounds__(256) void k_wprep(WMeta meta, ushort* __restrict__ Wm) {
    int which = blockIdx.y;
    int a = meta.ca[which], b = meta.cb[which];
    int tot = a * b * 9;
    int idx = blockIdx.x * 256 + threadIdx.x;
    if (idx >= tot) return;
    int t = idx % 9;
    int oi = idx / 9;
    int i = oi % b;
    int o = oi / b;
    ushort h = f2b(meta.src[which][idx]);   // K[o][i][t]
    Wm[meta.off_f[which] + ((size_t)t * a + o) * b + i] = h;
    Wm[meta.off_t[which] + ((size_t)(8 - t) * b + i) * a + o] = h;
}

// ---------- conv via MFMA, PG=2 p-tiles/block (Wm fragment loaded once) ----------
// grid (N/32, C_out/16); fused mask + per-block IN stat partials (NP = N/32).
__global__ __launch_bounds__(256) void k_convM(const ushort* __restrict__ yt,
                                               const ushort* __restrict__ Wm,
                                               float* __restrict__ zm,
                                               const float* __restrict__ m,
                                               float2* __restrict__ sp,
                                               int C_in, int C_out, int N,
                                               int iters, int NP) {
    __shared__ float lds[4][64][4];
    int t = threadIdx.x;
    int wv = t >> 6, l = t & 63;
    int prow = l & 15, kq = l >> 4;
    int p00 = blockIdx.x * 32;
    int o0 = blockIdx.y * 16;
    int per = (iters + 3) >> 2;
    int it0 = wv * per;
    int it1 = min(iters, it0 + per);
    f32x4 accA = (f32x4){0.f, 0.f, 0.f, 0.f};
    f32x4 accB = (f32x4){0.f, 0.f, 0.f, 0.f};
    for (int it = it0; it < it1; it++) {
        int ks = it / 9;
        int tp = it - ks * 9;
        int kb = ks * 32 + kq * 8;
        bf16x8 a = *(const bf16x8*)(Wm + ((size_t)tp * C_out + o0 + prow) * C_in + kb);
        bf16x8 bA = *(const bf16x8*)(yt + (size_t)(p00 + prow + tp) * C_in + kb);
        bf16x8 bB = *(const bf16x8*)(yt + (size_t)(p00 + 16 + prow + tp) * C_in + kb);
        accA = __builtin_amdgcn_mfma_f32_16x16x32_bf16(a, bA, accA, 0, 0, 0);
        accB = __builtin_amdgcn_mfma_f32_16x16x32_bf16(a, bB, accB, 0, 0, 0);
    }
    float stsum[4] = {0.f, 0.f, 0.f, 0.f}, stss[4] = {0.f, 0.f, 0.f, 0.f};
    #pragma unroll
    for (int pg = 0; pg < 2; pg++) {
        int p0 = p00 + pg * 16;
        #pragma unroll
        for (int r = 0; r < 4; r++) lds[wv][l][r] = (pg == 0) ? accA[r] : accB[r];
        __syncthreads();
        if (t < 64) {
            int g = t >> 4, j16 = t & 15;
            int j = p0 + j16;
            float mj = m[j];
            #pragma unroll
            for (int r = 0; r < 4; r++) {
                float z = lds[0][t][r] + lds[1][t][r] + lds[2][t][r] + lds[3][t][r];
                z *= mj;
                zm[(size_t)(o0 + g * 4 + r) * N + j] = z;
                float zs = z, zz = z * z;
                #pragma unroll
                for (int mask = 1; mask < 16; mask <<= 1) {
                    zs += __shfl_xor(zs, mask);
                    zz += __shfl_xor(zz, mask);
                }
                stsum[r] += zs; stss[r] += zz;
            }
        }
        __syncthreads();
    }
    if (t < 64 && (t & 15) == 0) {
        int g = t >> 4;
        #pragma unroll
        for (int r = 0; r < 4; r++)
            sp[(size_t)(o0 + g * 4 + r) * NP + blockIdx.x] = make_float2(stsum[r], stss[r]);
    }
}

// ---------- conv epilogue: global stats from NP partials + IN apply + relu + residual ----------
__global__ __launch_bounds__(256) void k_convC2(const float* __restrict__ zm,
                                                const float2* __restrict__ sp,
                                                const float* __restrict__ res,
                                                float* __restrict__ xout,
                                                ushort* __restrict__ xob, int N, int NP) {
    int o = blockIdx.y;
    int t = threadIdx.x;
    float2 pp = (t < NP) ? sp[(size_t)o * NP + t] : make_float2(0.f, 0.f);
    __shared__ float red[256], red2[256];
    red[t] = pp.x; red2[t] = pp.y;
    __syncthreads();
    for (int off = 128; off > 0; off >>= 1) {
        if (t < off) { red[t] += red[t + off]; red2[t] += red2[t + off]; }
        __syncthreads();
    }
    float mean = red[0] / N;
    float var = fmaxf(red2[0] / N - mean * mean, 0.f);
    float rs = rsqrtf(var + 1e-5f);
    int base = blockIdx.x * 512 + t * 2;
    float2 z = *(const float2*)(zm + (size_t)o * N + base);
    float v0 = fmaxf((z.x - mean) * rs, 0.f);
    float v1 = fmaxf((z.y - mean) * rs, 0.f);
    if (res) {
        float2 r = *(const float2*)(res + (size_t)o * N + base);
        v0 += r.x; v1 += r.y;
    }
    *(float2*)(xout + (size_t)o * N + base) = make_float2(v0, v1);
    if (xob) *(ushort2*)(xob + (size_t)o * N + base) = make_ushort2(f2b(v0), f2b(v1));
}

// ---------- fused pool (z rows + mask + X), z dual-written bf16 ----------
__global__ __launch_bounds__(256) void k_poolall(const float* __restrict__ z_in,
                                                 float* __restrict__ z_out,
                                                 ushort* __restrict__ zb_out, int Cz,
                                                 const float* __restrict__ m_in, float* __restrict__ m_out,
                                                 const float* __restrict__ X_in, float* __restrict__ X_out, int Nin) {
    int No = Nin >> 1;
    int idx = blockIdx.x * 256 + threadIdx.x;
    int total = (Cz + 4) * No;
    if (idx >= total) return;
    int r = idx / No, ii = idx - r * No;
    const float* src;
    if (r < Cz) {
        src = z_in + (size_t)r * Nin;
        float a = (ii > 0) ? src[2 * ii - 1] : 0.f;
        float v = (a + src[2 * ii] + src[2 * ii + 1]) * (1.f / 3.f);
        z_out[(size_t)r * No + ii] = v;
        zb_out[(size_t)r * No + ii] = f2b(v);
    } else if (r == Cz) {
        src = m_in;
        float a = (ii > 0) ? src[2 * ii - 1] : 0.f;
        m_out[ii] = (a + src[2 * ii] + src[2 * ii + 1]) * (1.f / 3.f);
    } else {
        src = X_in + (size_t)(r - Cz - 1) * Nin;
        float a = (ii > 0) ? src[2 * ii - 1] : 0.f;
        X_out[(size_t)(r - Cz - 1) * No + ii] = (a + src[2 * ii] + src[2 * ii + 1]) * (1.f / 3.f);
    }
}

// ---------- host ----------

extern "C" void kernel_launch(void* const* d_in, const int* in_sizes, int n_in,
                              void* d_out, int out_size, void* d_ws, size_t ws_size,
                              hipStream_t stream) {
    (void)in_sizes; (void)n_in; (void)out_size; (void)ws_size;
    const float* x_in = (const float*)d_in[0];
    const float* X0 = (const float*)d_in[1];
    const float* m0 = (const float*)d_in[2];
    const float* Kw[11];
    for (int i = 0; i < 11; i++) Kw[i] = (const float*)d_in[3 + i];
    float* out = (float*)d_out;
    float* ws = (float*)d_ws;

    const int Ns[4] = {4096, 2048, 1024, 512};
    const int KA[11] = {32, 32, 64, 64, 64, 128, 128, 128, 256, 256, 256};
    const int KB[11] = {32, 32, 32, 64, 64, 64, 128, 128, 128, 256, 256};

    size_t off = 0;
    auto alloc = [&](size_t n) { float* p = ws + off; off += (n + 63) & ~(size_t)63; return p; };
    ushort* Lb[4];
    Lb[0] = (ushort*)alloc(8388608); Lb[1] = (ushort*)alloc(2097152);
    Lb[2] = (ushort*)alloc(524288);  Lb[3] = (ushort*)alloc(131072);
    float* Xnb = alloc(3 * 4096);
    float* sqb = alloc(4096);
    float* spbuf = alloc(32768);
    float* zmbuf = alloc(262144);
    float* mlev[4];
    mlev[0] = const_cast<float*>(m0);
    mlev[1] = alloc(2048); mlev[2] = alloc(1024); mlev[3] = alloc(512);
    float* Xlev[4];
    Xlev[0] = const_cast<float*>(X0);
    Xlev[1] = alloc(3 * 2048); Xlev[2] = alloc(3 * 1024); Xlev[3] = alloc(3 * 512);
    float* pA[4], *pB[4], *xs[3];
    for (int l = 0; l < 4; l++) { pA[l] = alloc(131072); pB[l] = alloc(131072); }
    for (int l = 0; l < 3; l++) xs[l] = alloc(131072);
    float* zbig = alloc(262144);
    ushort* pAb[4], *pBb[4], *xsb[3];
    for (int l = 0; l < 4; l++) { pAb[l] = (ushort*)alloc(65536); pBb[l] = (ushort*)alloc(65536); }
    for (int l = 0; l < 3; l++) xsb[l] = (ushort*)alloc(65536);
    ushort* ytb = (ushort*)alloc(140000);
    ushort* Wm = (ushort*)alloc(1960000);

    size_t woff_f[11], woff_t[11];
    {
        size_t acc = 0;
        for (int k = 0; k < 11; k++) { woff_f[k] = acc; acc += (size_t)KA[k] * KB[k] * 9; }
        for (int k = 0; k < 11; k++) { woff_t[k] = acc; acc += (size_t)KA[k] * KB[k] * 9; }
    }

    {
        WMeta meta;
        for (int k = 0; k < 11; k++) {
            meta.src[k] = Kw[k];
            meta.off_f[k] = woff_f[k];
            meta.off_t[k] = woff_t[k];
            meta.ca[k] = KA[k];
            meta.cb[k] = KB[k];
        }
        k_wprep<<<dim3(2304, 11), 256, 0, stream>>>(meta, Wm);
    }

    auto build_lap = [&](int lvl) {
        int N = Ns[lvl];
        k_prep<<<1, 256, 0, stream>>>(Xlev[lvl], Xnb, sqb, N);
        if (N == 4096)      k_lap<16><<<N, 256, 0, stream>>>(Xnb, sqb, mlev[lvl], Lb[lvl], N);
        else if (N == 2048) k_lap<8><<<N, 256, 0, stream>>>(Xnb, sqb, mlev[lvl], Lb[lvl], N);
        else if (N == 1024) k_lap<4><<<N, 256, 0, stream>>>(Xnb, sqb, mlev[lvl], Lb[lvl], N);
        else                k_lap<4><<<N, 128, 0, stream>>>(Xnb, sqb, mlev[lvl], Lb[lvl], N);
    };

    // mode 0: bf16 src; mode 1: f32 src; mode 2: bf16 half-N repeat src
    auto matmul = [&](const void* xsrc, int C, int lvl, int mode) {
        int N = Ns[lvl];
        dim3 g(N / 16, C / 32);
        if (mode == 0)      k_mmfT<0><<<g, 256, 0, stream>>>(xsrc, Lb[lvl], ytb, N, C);
        else if (mode == 1) k_mmfT<1><<<g, 256, 0, stream>>>(xsrc, Lb[lvl], ytb, N, C);
        else                k_mmfT<2><<<g, 256, 0, stream>>>(xsrc, Lb[lvl], ytb, N, C);
    };

    auto conv = [&](int kidx, int lvl, const float* resv, float* ov, ushort* ovb,
                    int Cin, int Cout, int tr) {
        int N = Ns[lvl];
        int iters = (Cin / 32) * 9;
        int NP = N / 32;
        const ushort* wm = Wm + (tr ? woff_t[kidx] : woff_f[kidx]);
        k_convM<<<dim3(N / 32, Cout / 16), 256, 0, stream>>>(ytb, wm, zmbuf, mlev[lvl],
                                                             (float2*)spbuf, Cin, Cout, N, iters, NP);
        int NBs = N / 512;
        k_convC2<<<dim3(NBs, Cout), 256, 0, stream>>>(zmbuf, (const float2*)spbuf, resv, ov, ovb, N, NP);
    };

    auto poolall = [&](const float* z_in, float* z_out, ushort* zb_out, int Cz, int lvl_from) {
        int Nin = Ns[lvl_from];
        int No = Nin >> 1;
        int total = (Cz + 4) * No;
        k_poolall<<<(total + 255) / 256, 256, 0, stream>>>(z_in, z_out, zb_out, Cz,
                                                           mlev[lvl_from], mlev[lvl_from + 1],
                                                           Xlev[lvl_from], Xlev[lvl_from + 1], Nin);
    };

    // ---- down ----
    build_lap(0);
    matmul(x_in, 32, 0, 1);    conv(0, 0, x_in, pA[0], pAb[0], 32, 32, 0);
    matmul(pAb[0], 32, 0, 0);  conv(1, 0, pA[0], xs[0], xsb[0], 32, 32, 0);
    matmul(xsb[0], 32, 0, 0);  conv(2, 0, nullptr, zbig, nullptr, 32, 64, 0);
    poolall(zbig, pA[1], pAb[1], 64, 0);
    build_lap(1);
    matmul(pAb[1], 64, 1, 0);  conv(3, 1, pA[1], pB[1], pBb[1], 64, 64, 0);
    matmul(pBb[1], 64, 1, 0);  conv(4, 1, pB[1], xs[1], xsb[1], 64, 64, 0);
    matmul(xsb[1], 64, 1, 0);  conv(5, 1, nullptr, zbig, nullptr, 64, 128, 0);
    poolall(zbig, pA[2], pAb[2], 128, 1);
    build_lap(2);
    matmul(pAb[2], 128, 2, 0); conv(6, 2, pA[2], pB[2], pBb[2], 128, 128, 0);
    matmul(pBb[2], 128, 2, 0); conv(7, 2, pB[2], xs[2], xsb[2], 128, 128, 0);
    matmul(xsb[2], 128, 2, 0); conv(8, 2, nullptr, zbig, nullptr, 128, 256, 0);
    poolall(zbig, pA[3], pAb[3], 256, 2);
    build_lap(3);
    matmul(pAb[3], 256, 3, 0); conv(9, 3, pA[3], pB[3], pBb[3], 256, 256, 0);
    matmul(pBb[3], 256, 3, 0); conv(10, 3, pB[3], pA[3], pAb[3], 256, 256, 0);

    // ---- up ----
    matmul(pAb[3], 256, 3, 0); conv(10, 3, pA[3], pB[3], pBb[3], 256, 256, 1);
    matmul(pBb[3], 256, 3, 0); conv(9, 3, pB[3], pA[3], pAb[3], 256, 256, 1);

    // fused repeat: pAb[3] (256x512) -> lvl2 matmul (256x1024)
    matmul(pAb[3], 256, 2, 2); conv(8, 2, xs[2], pB[2], pBb[2], 256, 128, 1);
    matmul(pBb[2], 128, 2, 0); conv(7, 2, pB[2], pA[2], pAb[2], 128, 128, 1);
    matmul(pAb[2], 128, 2, 0); conv(6, 2, pA[2], pB[2], pBb[2], 128, 128, 1);

    // fused repeat: pBb[2] (128x1024) -> lvl1 matmul (128x2048)
    matmul(pBb[2], 128, 1, 2); conv(5, 1, xs[1], pA[1], pAb[1], 128, 64, 1);
    matmul(pAb[1], 64, 1, 0);  conv(4, 1, pA[1], pB[1], pBb[1], 64, 64, 1);
    matmul(pBb[1], 64, 1, 0);  conv(3, 1, pB[1], pA[1], pAb[1], 64, 64, 1);

    // fused repeat: pAb[1] (64x2048) -> lvl0 matmul (64x4096)
    matmul(pAb[1], 64, 0, 2);  conv(2, 0, xs[0], pB[0], pBb[0], 64, 32, 1);
    matmul(pBb[0], 32, 0, 0);  conv(1, 0, pB[0], pA[0], pAb[0], 32, 32, 1);
    matmul(pAb[0], 32, 0, 0);  conv(0, 0, pA[0], out, nullptr, 32, 32, 1);
}